// Round 4
// baseline (2194.183 us; speedup 1.0000x reference)
//
#include <hip/hip_runtime.h>
#include <math.h>

// ---------- types / helpers ----------
typedef __attribute__((ext_vector_type(8))) short bf16x8;   // 8 bf16 = 4 VGPR
typedef __attribute__((ext_vector_type(4))) int   i32x4;
typedef __attribute__((ext_vector_type(4))) float f32x4;    // MFMA acc
typedef __attribute__((ext_vector_type(4))) unsigned short u16x4;

__device__ __forceinline__ unsigned short f2bf(float x) {   // round-to-nearest-even
  unsigned int u = __builtin_bit_cast(unsigned int, x);
  return (unsigned short)((u + 0x7fffu + ((u >> 16) & 1u)) >> 16);
}
__device__ __forceinline__ float bf2f(unsigned short h) {
  unsigned int u = ((unsigned int)h) << 16;
  return __builtin_bit_cast(float, u);
}
// tanh via hw exp2: tanh(z) = 1 - 2/(e^{2z}+1)
__device__ __forceinline__ float fast_tanh(float z) {
  float e;
  asm("v_exp_f32 %0, %1" : "=v"(e) : "v"(z * 2.8853900817779268f));
  return 1.0f - 2.0f * __builtin_amdgcn_rcpf(e + 1.0f);
}

// ---------- K0: convert weights to bf16; seed hx slices ----------
// regions (elem units, e = idx*4):
//   [0, 2097152)          w_i2h -> wx | wh
//   [2097152, 3145728)    w_h2o -> w2o
//   [3145728, 3211264)    h0 -> hx slice0, tag bits = 00
//   [3211264, 3276800)    hx slice1 <- 0x0003 (invalid tag 0b11)
__global__ void convert_kernel(const float* __restrict__ w_i2h,
                               const float* __restrict__ w_h2o,
                               const float* __restrict__ h0,
                               unsigned short* __restrict__ wx,
                               unsigned short* __restrict__ wh,
                               unsigned short* __restrict__ w2o,
                               unsigned short* __restrict__ hx) {
  int idx = blockIdx.x * 256 + threadIdx.x;
  int e = idx * 4;
  if (e >= 3276800) return;
  if (e >= 3211264) {                      // hx slice1 invalid fill
    *(u16x4*)(hx + 65536 + (e - 3211264)) = (u16x4){3, 3, 3, 3};
    return;
  }
  const float* src;
  unsigned short* dst;
  bool tag0 = false;
  if (e < 2097152) {                       // w_i2h
    int row = e >> 11, col = e & 2047;
    src = w_i2h + e;
    dst = (col < 1024) ? (wx + row * 1024 + col) : (wh + row * 1024 + (col - 1024));
  } else if (e < 3145728) {                // w_h2o
    int i = e - 2097152; src = w_h2o + i; dst = w2o + i;
  } else {                                 // h0 -> hx slice0 (tagged 00)
    int i = e - 3145728; src = h0 + i; dst = hx + i; tag0 = true;
  }
  float4 v = *(const float4*)src;
  u16x4 o = {f2bf(v.x), f2bf(v.y), f2bf(v.z), f2bf(v.w)};
  if (tag0) {
    o[0] &= 0xFFFC; o[1] &= 0xFFFC; o[2] &= 0xFFFC; o[3] &= 0xFFFC;
  }
  *(u16x4*)dst = o;
}

// ---------- GEMM: C[M,N] = A[M,K] * B[N,K]^T + bias[N] ----------
// 128x128 tile, BK=64, 4 waves (2x2 of 64x64), 16x16x32 bf16 MFMA.
template <bool AF32, bool OUTBF16>
__global__ __launch_bounds__(256) void gemm_bt(const void* __restrict__ Ap,
                                               const unsigned short* __restrict__ B,
                                               const float* __restrict__ bias,
                                               void* __restrict__ Cp,
                                               int M, int N, int K) {
  __shared__ __attribute__((aligned(16))) unsigned short lA[128 * 64];
  __shared__ __attribute__((aligned(16))) unsigned short lB[128 * 64];
  const int tid = threadIdx.x;
  const int bx = blockIdx.x & 7;       // N/128 == 8
  const int by = blockIdx.x >> 3;
  const int lane = tid & 63, w = tid >> 6;
  const int g = lane >> 4, l15 = lane & 15;
  const int wm = w >> 1, wn = w & 1;

  f32x4 acc[4][4];
#pragma unroll
  for (int i = 0; i < 4; ++i)
#pragma unroll
    for (int j = 0; j < 4; ++j) acc[i][j] = (f32x4){0.f, 0.f, 0.f, 0.f};

  const int nK = K >> 6;
  for (int kt = 0; kt < nK; ++kt) {
    const int k0 = kt << 6;
#pragma unroll
    for (int i = 0; i < 4; ++i) {
      int cl = i * 256 + tid;
      int row = cl >> 3, cc = cl & 7;
      bf16x8 av;
      if (AF32) {
        const float* ap = (const float*)Ap + (size_t)(by * 128 + row) * K + k0 + cc * 8;
        float4 f0 = *(const float4*)ap;
        float4 f1 = *(const float4*)(ap + 4);
        av = (bf16x8){(short)f2bf(f0.x), (short)f2bf(f0.y), (short)f2bf(f0.z), (short)f2bf(f0.w),
                      (short)f2bf(f1.x), (short)f2bf(f1.y), (short)f2bf(f1.z), (short)f2bf(f1.w)};
      } else {
        const unsigned short* ap = (const unsigned short*)Ap + (size_t)(by * 128 + row) * K + k0 + cc * 8;
        av = *(const bf16x8*)ap;
      }
      *(bf16x8*)&lA[(row * 8 + (cc ^ (row & 7))) * 8] = av;
      const unsigned short* bp = B + (size_t)(bx * 128 + row) * K + k0 + cc * 8;
      bf16x8 bv = *(const bf16x8*)bp;
      *(bf16x8*)&lB[(row * 8 + (cc ^ (row & 7))) * 8] = bv;
    }
    __syncthreads();
#pragma unroll
    for (int kk = 0; kk < 2; ++kk) {
      bf16x8 av[4], bv[4];
#pragma unroll
      for (int mt = 0; mt < 4; ++mt) {
        int r = wm * 64 + mt * 16 + l15;
        av[mt] = *(const bf16x8*)&lA[(r * 8 + ((kk * 4 + g) ^ (r & 7))) * 8];
      }
#pragma unroll
      for (int nt = 0; nt < 4; ++nt) {
        int r = wn * 64 + nt * 16 + l15;
        bv[nt] = *(const bf16x8*)&lB[(r * 8 + ((kk * 4 + g) ^ (r & 7))) * 8];
      }
#pragma unroll
      for (int mt = 0; mt < 4; ++mt)
#pragma unroll
        for (int nt = 0; nt < 4; ++nt)
          acc[mt][nt] = __builtin_amdgcn_mfma_f32_16x16x32_bf16(av[mt], bv[nt], acc[mt][nt], 0, 0, 0);
    }
    __syncthreads();
  }
#pragma unroll
  for (int mt = 0; mt < 4; ++mt) {
    int grow = by * 128 + wm * 64 + mt * 16 + g * 4;
#pragma unroll
    for (int nt = 0; nt < 4; ++nt) {
      int col = bx * 128 + wn * 64 + nt * 16 + l15;
      float bs = bias[col];
#pragma unroll
      for (int r = 0; r < 4; ++r) {
        size_t off = (size_t)(grow + r) * N + col;
        float v = acc[mt][nt][r] + bs;
        if (OUTBF16) ((unsigned short*)Cp)[off] = f2bf(v);
        else ((float*)Cp)[off] = v;
      }
    }
  }
}

// ---------- K2: persistent scan with self-validating tagged exchange ----------
// 256 blocks x 64 threads (1 wave). Block b: jt=b>>2 (16 j's), bt=b&3 (16 batches).
// h exchange via hx[2][64][1024] bf16 ping-pong (slice t&1); each bf16 carries a
// 2-bit tag in mantissa LSBs: {0, (t>>1)&1}. A 16B chunk is fresh iff all 8 tags
// match -> data IS the flag: no drains, no flag array, no separate detect RT.
// Lag between blocks is bounded at 1 step (producer can't overwrite slice p
// before all peers consumed its previous occupant), so 1-bit-of-2 tags suffice.
// Poison 0xAA (tag 0b10) and convert's slice1 fill (0b11) never validate.
#define SCAN_BLOCKS 256
__global__ __launch_bounds__(64, 1) void rnn_scan(const unsigned short* __restrict__ xproj,
                                                  const unsigned short* __restrict__ wh,
                                                  unsigned short* __restrict__ h_all,
                                                  unsigned short* __restrict__ hx) {
  const int tid = threadIdx.x;          // 0..63
  const int b = blockIdx.x;
  const int jt = b >> 2, bt = b & 3;
  const int g = tid >> 4, l15 = tid & 15;
  const int j0 = jt * 16, b0 = bt * 16;

  // A-fragments (wh rows j0..j0+15, step-invariant, in VGPR for all 512 steps)
  bf16x8 wa[32];
#pragma unroll
  for (int kk = 0; kk < 32; ++kk)
    wa[kk] = *(const bf16x8*)(wh + (size_t)(j0 + l15) * 1024 + kk * 32 + g * 8);

  const int rowoff = (b0 + l15) * 1024;      // this lane's h row base (elems)
  const int cbase  = rowoff + g * 8;         // chunk-load base (+kk*32)
  const int pofs   = rowoff + j0 + g * 4;    // producer/xp offset (4 j-consecutive)

  unsigned short* hx0 = hx;
  unsigned short* hx1 = hx + 65536;

  // prologue: xp for t=0
  uint2 xpc = *(const uint2*)(xproj + pofs);

  for (int t = 0; t < 512; ++t) {
    const unsigned short* src = (t & 1) ? hx1 : hx0;
    unsigned short*       dst = (t & 1) ? hx0 : hx1;
    const unsigned int pat2 = (unsigned int)((t >> 1) & 1) * 0x00010001u;

    // --- load + validate h[t] chunks (retry until all tags match) ---
    i32x4 c[32];
    bool allok;
    do {
#pragma unroll
      for (int kk = 0; kk < 32; ++kk) {
        const unsigned short* p = src + cbase + kk * 32;
        asm volatile("global_load_dwordx4 %0, %1, off sc0 sc1"
                     : "=v"(c[kk]) : "v"(p) : "memory");
      }
      asm volatile("s_waitcnt vmcnt(0)" ::: "memory");
      __builtin_amdgcn_sched_barrier(0);
      unsigned int bad = 0;
#pragma unroll
      for (int kk = 0; kk < 32; ++kk) {
        bad |= ((unsigned int)c[kk][0] ^ pat2) & 0x00030003u;
        bad |= ((unsigned int)c[kk][1] ^ pat2) & 0x00030003u;
        bad |= ((unsigned int)c[kk][2] ^ pat2) & 0x00030003u;
        bad |= ((unsigned int)c[kk][3] ^ pat2) & 0x00030003u;
      }
      allok = (bad == 0);
    } while (__any(!allok));
    __builtin_amdgcn_sched_barrier(0);

    // prefetch next step's xp (plain cached; lands during next sync cycle)
    int tn = (t < 511) ? (t + 1) : 511;
    uint2 xpn = *(const uint2*)(xproj + (size_t)tn * 65536 + pofs);

    // --- MFMA: D[j][batch] = wh_slice x h^T  (operand-swapped) ---
    f32x4 acc[4];
#pragma unroll
    for (int i = 0; i < 4; ++i) acc[i] = (f32x4){0.f, 0.f, 0.f, 0.f};
#pragma unroll
    for (int kk = 0; kk < 32; ++kk)
      acc[kk & 3] = __builtin_amdgcn_mfma_f32_16x16x32_bf16(
          wa[kk], __builtin_bit_cast(bf16x8, c[kk]), acc[kk & 3], 0, 0, 0);
    f32x4 s = (acc[0] + acc[1]) + (acc[2] + acc[3]);

    // --- epilogue: lane holds h_next[b0+l15][j0+g*4 .. +3] ---
    const unsigned int tagn = (unsigned int)(((t + 1) >> 1) & 1);
    unsigned int v01, v23;
    {
      float z0 = s[0] + bf2f((unsigned short)(xpc.x & 0xFFFF));
      float z1 = s[1] + bf2f((unsigned short)(xpc.x >> 16));
      float z2 = s[2] + bf2f((unsigned short)(xpc.y & 0xFFFF));
      float z3 = s[3] + bf2f((unsigned short)(xpc.y >> 16));
      unsigned int h0v = (f2bf(fast_tanh(z0)) & 0xFFFCu) | tagn;
      unsigned int h1v = (f2bf(fast_tanh(z1)) & 0xFFFCu) | tagn;
      unsigned int h2v = (f2bf(fast_tanh(z2)) & 0xFFFCu) | tagn;
      unsigned int h3v = (f2bf(fast_tanh(z3)) & 0xFFFCu) | tagn;
      v01 = h0v | (h1v << 16);
      v23 = h2v | (h3v << 16);
    }
    uint2 dvec = {v01, v23};
    // coherent exchange store (fire-and-forget, no drain)
    unsigned short* pd = dst + pofs;
    asm volatile("global_store_dwordx2 %0, %1, off sc0 sc1"
                 :: "v"(pd), "v"(dvec) : "memory");
    // dense h for the output GEMM (plain store; visible to gemm2 at kernel end)
    *(uint2*)(h_all + (size_t)t * 65536 + pofs) = dvec;

    xpc = xpn;
  }
}

// ---------- launch ----------
extern "C" void kernel_launch(void* const* d_in, const int* in_sizes, int n_in,
                              void* d_out, int out_size, void* d_ws, size_t ws_size,
                              hipStream_t stream) {
  const float* x     = (const float*)d_in[0];   // (512,64,1024)
  const float* h0    = (const float*)d_in[1];   // (64,1024)
  const float* w_i2h = (const float*)d_in[2];   // (1024,2048)
  const float* b_i2h = (const float*)d_in[3];   // (1024)
  const float* w_h2o = (const float*)d_in[4];   // (1024,1024)
  const float* b_h2o = (const float*)d_in[5];   // (1024)

  // workspace: h_all h[1..512] (512*65536*2B = 67,108,864) | hx 2 slices (262,144)
  //            | wx 2MB | wh 2MB | w2o 2MB   (~73.7 MB)
  char* ws = (char*)d_ws;
  unsigned short* h_all = (unsigned short*)ws;
  unsigned short* hx    = (unsigned short*)(ws + 67108864);
  unsigned short* wx    = (unsigned short*)(ws + 67108864 + 262144);
  unsigned short* wh    = wx + 1024 * 1024;
  unsigned short* w2o   = wh + 1024 * 1024;
  // d_out (128MB fp32 y): first 64MB doubles as bf16 xproj (dead before gemm2).
  unsigned short* xproj = (unsigned short*)d_out;

  convert_kernel<<<3200, 256, 0, stream>>>(w_i2h, w_h2o, h0, wx, wh, w2o, hx);

  // xproj = x @ wx^T + b_i2h   (M=32768, N=1024, K=1024)
  gemm_bt<true, true><<<2048, 256, 0, stream>>>((const void*)x, wx, b_i2h,
                                                (void*)xproj, 32768, 1024, 1024);

  // persistent 512-step recurrence (tag-validated exchange, no barriers)
  rnn_scan<<<SCAN_BLOCKS, 64, 0, stream>>>(xproj, wh, h_all, hx);

  // Y = h_all (= h[1..512]) @ w_h2o^T + b_h2o  -> d_out (fp32)
  gemm_bt<false, false><<<2048, 256, 0, stream>>>((const void*)h_all, w2o, b_h2o,
                                                  d_out, 32768, 1024, 1024);
}